// Round 13
// baseline (208.337 us; speedup 1.0000x reference)
//
#include <hip/hip_runtime.h>
#include <hip/hip_bf16.h>
#include <math.h>

typedef __attribute__((ext_vector_type(8))) short short8;
typedef __attribute__((ext_vector_type(4))) float float4v;
typedef unsigned short ushort_t;

constexpr int NPTS = 32768;  // B*N
constexpr int NN   = 16384;  // points per batch
constexpr int KK   = 32;     // neighbors
constexpr int CC   = 128;    // channels
constexpr int GRP  = 16;     // points per block in gather kernel -> grid 2048
constexpr int SR   = 132;    // res LDS row stride (shorts): 264 B -> 2-way banks (free)
#define LN_EPS 1e-5f

// d_ws layout (bytes) — total 8462336 B (same footprint as validated R12)
constexpr size_t WS_PG = 0;        // PG = w_pos@w_gcm: 10*128 f32 = 5120 B
constexpr size_t WS_BE = 5120;     // beff: 128 f32 = 512 B
constexpr size_t WS_WP = 8192;     // w_gcm swizzled bf16 [(k/8)(n)(k%8)]: 32768 B
constexpr size_t WS_WO = 40960;    // w_out swizzled bf16: 32768 B
constexpr size_t WS_FW = 73728;    // FW2 = F@w_gcm + nbr-geo, bf16 [32768][128]: 8388608 B

__device__ __forceinline__ short f2bs(float x) {
    return (short)__builtin_bit_cast(unsigned short, __float2bfloat16(x));
}
__device__ __forceinline__ float bs2f(ushort_t u) {
    return __uint_as_float(((unsigned)u) << 16);
}

// ---------------- prep: PG fold + beff + weight swizzles (13 blocks x 128) ----------------
__global__ __launch_bounds__(128) void prep_fold(
    const float* __restrict__ w_pos, const float* __restrict__ b_pos,
    const float* __restrict__ w_gcm, const float* __restrict__ b_gcm,
    const float* __restrict__ w_out,
    float* __restrict__ wsPG, float* __restrict__ wsBeff,
    short* __restrict__ wsWp, short* __restrict__ wsWo)
{
    const int c = threadIdx.x, g = blockIdx.x;
    if (g < 10) {
        float s = 0.f;
        #pragma unroll
        for (int r = 0; r < 128; ++r) s += w_pos[g * 128 + r] * w_gcm[r * 128 + c];
        wsPG[g * 128 + c] = s;
        return;
    }
    if (g == 10) {
        float s = b_gcm[c];
        #pragma unroll
        for (int r = 0; r < 128; ++r) s += b_pos[r] * w_gcm[r * 128 + c];
        wsBeff[c] = s;
        return;
    }
    if (g == 11) {   // w_gcm -> [(k/8)(n)(k%8)] bf16
        #pragma unroll 4
        for (int e = c; e < 16 * 128 * 8; e += 128) {
            const int j = e & 7, n = (e >> 3) & 127, kg = e >> 10;
            wsWp[e] = f2bs(w_gcm[(kg * 8 + j) * 128 + n]);
        }
        return;
    }
    // g == 12: w_out swizzle
    #pragma unroll 4
    for (int e = c; e < 16 * 128 * 8; e += 128) {
        const int j = e & 7, n = (e >> 3) & 127, kg = e >> 10;
        wsWo[e] = f2bs(w_out[(kg * 8 + j) * 128 + n]);
    }
}

// ---------------- FW2 = F @ w_gcm + nbr_xyz . pgb  (bf16 MFMA + geo fold; 1024 blocks x 256) ----------------
__global__ __launch_bounds__(256) void fw_gemm(
    const float* __restrict__ F, const float* __restrict__ points,
    const float* __restrict__ wsPG, const short* __restrict__ wsWp,
    ushort_t* __restrict__ fwbf)
{
    const int t = threadIdx.x, wv = t >> 6;
    const int quad = (t >> 4) & 3, m = t & 15;
    const int rg = wv >> 1, ch = wv & 1;
    const int r0 = blockIdx.x * 32 + rg * 16;

    short8 bW[4][4];
    #pragma unroll
    for (int ks = 0; ks < 4; ++ks)
        #pragma unroll
        for (int n = 0; n < 4; ++n)
            bW[ks][n] = ((const short8*)wsWp)[(ks * 4 + quad) * 128 + ch * 64 + n * 16 + m];

    // pgb[j][n] for this thread's 4 columns (c = ch*64 + n*16 + m)
    float pgb[3][4];
    #pragma unroll
    for (int n = 0; n < 4; ++n) {
        const int c = ch * 64 + n * 16 + m;
        pgb[0][n] = wsPG[3 * 128 + c] + wsPG[6 * 128 + c];
        pgb[1][n] = wsPG[4 * 128 + c] + wsPG[7 * 128 + c];
        pgb[2][n] = wsPG[5 * 128 + c] + wsPG[8 * 128 + c];
    }

    // A fragments: row m of this row-group (f32 -> bf16 cvt)
    const float* fr = F + (size_t)(r0 + m) * CC;
    short8 A[4];
    #pragma unroll
    for (int ks = 0; ks < 4; ++ks) {
        const float4 x = *(const float4*)(fr + ks * 32 + quad * 8);
        const float4 y = *(const float4*)(fr + ks * 32 + quad * 8 + 4);
        short8 v;
        v[0]=f2bs(x.x); v[1]=f2bs(x.y); v[2]=f2bs(x.z); v[3]=f2bs(x.w);
        v[4]=f2bs(y.x); v[5]=f2bs(y.y); v[6]=f2bs(y.z); v[7]=f2bs(y.w);
        A[ks] = v;
    }

    float4v acc[4] = {};
    #pragma unroll
    for (int ks = 0; ks < 4; ++ks)
        #pragma unroll
        for (int n = 0; n < 4; ++n)
            acc[n] = __builtin_amdgcn_mfma_f32_16x16x32_bf16(A[ks], bW[ks][n], acc[n], 0, 0, 0);

    // C layout: col = m, row = quad*4 + r.  Fold neighbor-geo term before bf16 store.
    #pragma unroll
    for (int r = 0; r < 4; ++r) {
        const int row = r0 + quad * 4 + r;
        const float px = points[(size_t)row * 3 + 0];
        const float py = points[(size_t)row * 3 + 1];
        const float pz = points[(size_t)row * 3 + 2];
        #pragma unroll
        for (int n = 0; n < 4; ++n) {
            const float v = acc[n][r] + px * pgb[0][n] + py * pgb[1][n] + pz * pgb[2][n];
            fwbf[(size_t)row * CC + ch * 64 + n * 16 + m] = (ushort_t)(unsigned short)f2bs(v);
        }
    }
}

// ---------------- main: minimal gather-max + MFMA out-proj + LN ----------------
// block 256 thr = two 128-thr sub-blocks; sub s handles points s*8..s*8+7, thread = column c.
__global__ __launch_bounds__(256) void bridge_gather(
    const float* __restrict__ points, const float* __restrict__ features,
    const int*   __restrict__ gidx,
    const float* __restrict__ wsPG, const float* __restrict__ wsBeff,
    const ushort_t* __restrict__ fwbf, const short* __restrict__ wsWo,
    const float* __restrict__ b_out, const float* __restrict__ ln_g,
    const float* __restrict__ ln_b,
    float* __restrict__ out)
{
    __shared__ int2   sOD[GRP * KK];      // {row*128, dist(bits)} per (p,k): 4096 B; epilogue: sPS/sPQ
    __shared__ float4 sCen[GRP];          // center xyz per point: 256 B
    __shared__ short  sRes[GRP * SR];     // 4224 B

    float* sPS = (float*)&sOD[0];         // [4][GRP] (epilogue only)
    float* sPQ = sPS + 4 * GRP;

    const int t = threadIdx.x, wv = t >> 6;
    const int quad = (t >> 4) & 3, m = t & 15;
    const int sub = t >> 7, c = t & 127;
    const int g0 = blockIdx.x * GRP;
    const int nbase = (g0 >= NN) ? NN : 0;

    // ---- setup: {gather offset, dist} per (p,k) ----
    #pragma unroll
    for (int e = t; e < GRP * KK; e += 256) {
        const int p = e >> 5;
        const int kn = gidx[(size_t)(g0 + p) * KK + (e & 31)];   // coalesced
        const int row = nbase + kn;
        const float dx = points[(size_t)row * 3 + 0] - points[(size_t)(g0 + p) * 3 + 0];
        const float dy = points[(size_t)row * 3 + 1] - points[(size_t)(g0 + p) * 3 + 1];
        const float dz = points[(size_t)row * 3 + 2] - points[(size_t)(g0 + p) * 3 + 2];
        const float dist = sqrtf(dx * dx + dy * dy + dz * dz);
        sOD[e] = make_int2(row << 7, __float_as_int(dist));
    }
    if (t < GRP) {
        sCen[t] = make_float4(points[(size_t)(g0 + t) * 3 + 0],
                              points[(size_t)(g0 + t) * 3 + 1],
                              points[(size_t)(g0 + t) * 3 + 2], 0.f);
    }

    // ---- per-thread folded geo columns ----
    const float pga0 = wsPG[0 * 128 + c] - wsPG[6 * 128 + c];
    const float pga1 = wsPG[1 * 128 + c] - wsPG[7 * 128 + c];
    const float pga2 = wsPG[2 * 128 + c] - wsPG[8 * 128 + c];
    const float pgd  = wsPG[9 * 128 + c];
    const float be   = wsBeff[c];

    __syncthreads();

    // ---- gather-max: per (k): ds_read_b64 + or + load_ushort + shift + fma + max ----
    for (int i = 0; i < GRP / 2; ++i) {
        const int p = sub * (GRP / 2) + i;
        const int2* od = sOD + p * KK;
        float acc = -INFINITY;
        #pragma unroll 16
        for (int k = 0; k < KK; ++k) {
            const int2 e = od[k];                                  // broadcast ds_read_b64
            const float fw = bs2f(fwbf[(unsigned)(e.x | c)]);      // coalesced 2B/lane
            acc = fmaxf(acc, fmaf(__int_as_float(e.y), pgd, fw));
        }
        const float4 cen = sCen[p];
        const float base = fmaf(cen.x, pga0, fmaf(cen.y, pga1, fmaf(cen.z, pga2, be)));
        const float pooled = fmaxf(acc + base, 0.f);
        const float res = pooled + features[(size_t)(g0 + p) * CC + c];
        sRes[p * SR + c] = f2bs(res);
    }
    __syncthreads();   // sRes complete; sOD dead -> sPS/sPQ overlay safe

    // ---- out projection: res(16x128) @ w_out(128x128) ----
    const int col0 = wv * 32 + m;
    short8 bWo[4][2];
    #pragma unroll
    for (int ks = 0; ks < 4; ++ks)
        #pragma unroll
        for (int ntl = 0; ntl < 2; ++ntl)
            bWo[ks][ntl] = ((const short8*)wsWo)[(ks * 4 + quad) * 128 + col0 + ntl * 16];

    const short* rm = sRes + m * SR;
    float4v acc2[2] = {};
    #pragma unroll
    for (int ks = 0; ks < 4; ++ks) {
        const short8 a = *(const short8*)(rm + ks * 32 + quad * 8);
        acc2[0] = __builtin_amdgcn_mfma_f32_16x16x32_bf16(a, bWo[ks][0], acc2[0], 0, 0, 0);
        acc2[1] = __builtin_amdgcn_mfma_f32_16x16x32_bf16(a, bWo[ks][1], acc2[1], 0, 0, 0);
    }

    const float boutv[2] = { b_out[col0], b_out[col0 + 16] };
    const float lngv[2]  = { ln_g[col0], ln_g[col0 + 16] };
    const float lnbv[2]  = { ln_b[col0], ln_b[col0 + 16] };

    #pragma unroll
    for (int r = 0; r < 4; ++r) {
        const float o0 = acc2[0][r] + boutv[0];
        const float o1 = acc2[1][r] + boutv[1];
        float ss = o0 + o1, qq = o0 * o0 + o1 * o1;
        #pragma unroll
        for (int d = 1; d < 16; d <<= 1) { ss += __shfl_xor(ss, d); qq += __shfl_xor(qq, d); }
        if (m == 0) { sPS[wv * GRP + quad * 4 + r] = ss; sPQ[wv * GRP + quad * 4 + r] = qq; }
    }
    __syncthreads();

    #pragma unroll
    for (int r = 0; r < 4; ++r) {
        const int R = quad * 4 + r;
        const float S = sPS[0 * GRP + R] + sPS[1 * GRP + R] + sPS[2 * GRP + R] + sPS[3 * GRP + R];
        const float Q = sPQ[0 * GRP + R] + sPQ[1 * GRP + R] + sPQ[2 * GRP + R] + sPQ[3 * GRP + R];
        const float mu  = S * (1.f / 128.f);
        const float var = fmaxf(Q * (1.f / 128.f) - mu * mu, 0.f);
        const float rstd = rsqrtf(var + LN_EPS);
        const float o0 = acc2[0][r] + boutv[0];
        const float o1 = acc2[1][r] + boutv[1];
        const size_t base = (size_t)(g0 + R) * CC;
        out[base + col0]      = fmaxf((o0 - mu) * rstd * lngv[0] + lnbv[0], 0.f);
        out[base + col0 + 16] = fmaxf((o1 - mu) * rstd * lngv[1] + lnbv[1], 0.f);
    }
}

extern "C" void kernel_launch(void* const* d_in, const int* in_sizes, int n_in,
                              void* d_out, int out_size, void* d_ws, size_t ws_size,
                              hipStream_t stream) {
    const float* points   = (const float*)d_in[0];
    const float* features = (const float*)d_in[1];
    const int*   gidx     = (const int*)  d_in[2];
    const float* w_pos    = (const float*)d_in[3];
    const float* b_pos    = (const float*)d_in[4];
    const float* w_gcm    = (const float*)d_in[5];
    const float* b_gcm    = (const float*)d_in[6];
    const float* w_out    = (const float*)d_in[7];
    const float* b_out    = (const float*)d_in[8];
    const float* ln_g     = (const float*)d_in[9];
    const float* ln_b     = (const float*)d_in[10];
    float* out = (float*)d_out;

    char* ws = (char*)d_ws;
    float*    wsPG   = (float*)(ws + WS_PG);
    float*    wsBeff = (float*)(ws + WS_BE);
    short*    wsWp   = (short*)(ws + WS_WP);
    short*    wsWo   = (short*)(ws + WS_WO);
    ushort_t* fwbf   = (ushort_t*)(ws + WS_FW);

    hipLaunchKernelGGL(prep_fold, dim3(13), dim3(128), 0, stream,
                       w_pos, b_pos, w_gcm, b_gcm, w_out, wsPG, wsBeff, wsWp, wsWo);
    hipLaunchKernelGGL(fw_gemm, dim3(NPTS / 32), dim3(256), 0, stream,
                       features, points, wsPG, wsWp, fwbf);
    hipLaunchKernelGGL(bridge_gather, dim3(NPTS / GRP), dim3(256), 0, stream,
                       points, features, gidx, wsPG, wsBeff, fwbf, wsWo,
                       b_out, ln_g, ln_b, out);
}